// Round 1
// baseline (224.584 us; speedup 1.0000x reference)
//
#include <hip/hip_runtime.h>

#define NB    4
#define NPB   8192
#define NPTS  (NB*NPB)      // 32768
#define KNB   32
#define CH    64
#define W1COLS 67
#define GRPS  8
#define EPSV  1e-5f
#define SLOPEV 0.1f

// workspace layout (float offsets)
#define WS_STATS1 0
#define WS_STATS2 64
#define WS_STATS3 128
#define WS_FLAG   192          // int flag: 1 => edges are int32
#define WS_Y      256
#define WS_MX     (WS_Y  + NPTS*CH)
#define WS_MN     (WS_MX + NPTS*CH)
// z2pre reuses WS_Y region; z3pre reuses WS_MX region

// ---------------------------------------------------------------- dtype probe
__global__ __launch_bounds__(256) void k_detect(const unsigned long long* __restrict__ e,
                                                int n, int* __restrict__ flag)
{
    int stride = gridDim.x * blockDim.x;
    bool bad = false;
    for (int i = blockIdx.x * blockDim.x + threadIdx.x; i < n; i += stride)
        if (e[i] >= (unsigned long long)NPTS) bad = true;
    if (bad) atomicOr(flag, 1);
}

// ---------------------------------------------------------------- Y = sig * W1s^T
__global__ __launch_bounds__(256) void k_y(const float* __restrict__ sig,
                                           const float* __restrict__ W1,
                                           float* __restrict__ Y)
{
    __shared__ float w1t[CH*CH];          // w1t[c*64+m] = W1[m][c]
    int tid = threadIdx.x;
    for (int i = tid; i < CH*CH; i += 256) {
        int c = i >> 6, m = i & 63;
        w1t[i] = W1[m*W1COLS + c];
    }
    __syncthreads();
    int lane = tid & 63, w = tid >> 6;
    int p0 = blockIdx.x * 64 + w * 16;    // 16 points per wave, 64 per block
    for (int pi = 0; pi < 16; ++pi) {
        int p = p0 + pi;
        float sv = sig[p*CH + lane];
        float acc = 0.f;
        #pragma unroll
        for (int c = 0; c < CH; ++c)
            acc = fmaf(__shfl(sv, c, 64), w1t[c*CH + lane], acc);
        Y[p*CH + lane] = acc;
    }
}

// ---------------------------------------------------------------- edge pass
template<bool IS32>
__device__ __forceinline__ void edge_loop(const float* __restrict__ Y,
    const void* __restrict__ edges, const float* __restrict__ ef,
    float we0, float we1, float we2, int lane, int p0, int ppw,
    float* __restrict__ Mx, float* __restrict__ Mn, float& s, float& ss)
{
    const int*       e32 = (const int*)edges;
    const long long* e64 = (const long long*)edges;
    for (int pi = 0; pi < ppw; ++pi) {
        int p = p0 + pi;
        float yp = Y[p*CH + lane];
        float mx = -3.4e38f, mn = 3.4e38f;
        #pragma unroll 4
        for (int k = 0; k < KNB; ++k) {
            int ei = p*KNB + k;
            int e  = IS32 ? e32[ei] : (int)e64[ei];
            float c0 = ef[ei*3+0], c1 = ef[ei*3+1], c2 = ef[ei*3+2];
            float t = Y[e*CH + lane] - yp;
            t = fmaf(c0, we0, t);
            t = fmaf(c1, we1, t);
            t = fmaf(c2, we2, t);
            mx = fmaxf(mx, t);
            mn = fminf(mn, t);
            s += t;
            ss = fmaf(t, t, ss);
        }
        Mx[p*CH + lane] = mx;
        Mn[p*CH + lane] = mn;
    }
}

#define PPB_E 16
__global__ __launch_bounds__(256) void k_edge(const float* __restrict__ Y,
    const void* __restrict__ edges, const float* __restrict__ ef,
    const float* __restrict__ W1, const int* __restrict__ flag,
    float* __restrict__ Mx, float* __restrict__ Mn, float* __restrict__ stats1)
{
    __shared__ float lacc[GRPS*2];
    int tid = threadIdx.x, lane = tid & 63, w = tid >> 6;
    if (tid < GRPS*2) lacc[tid] = 0.f;
    float we0 = W1[lane*W1COLS + 64];
    float we1 = W1[lane*W1COLS + 65];
    float we2 = W1[lane*W1COLS + 66];
    bool is32 = (*flag != 0);
    __syncthreads();
    int p0 = blockIdx.x * PPB_E + w * (PPB_E/4);
    float s = 0.f, ss = 0.f;
    if (is32) edge_loop<true >(Y, edges, ef, we0, we1, we2, lane, p0, PPB_E/4, Mx, Mn, s, ss);
    else      edge_loop<false>(Y, edges, ef, we0, we1, we2, lane, p0, PPB_E/4, Mx, Mn, s, ss);
    s  += __shfl_xor(s, 1, 64);  ss += __shfl_xor(ss, 1, 64);
    s  += __shfl_xor(s, 2, 64);  ss += __shfl_xor(ss, 2, 64);
    s  += __shfl_xor(s, 4, 64);  ss += __shfl_xor(ss, 4, 64);
    if ((lane & 7) == 0) {
        atomicAdd(&lacc[(lane>>3)*2 + 0], s);
        atomicAdd(&lacc[(lane>>3)*2 + 1], ss);
    }
    __syncthreads();
    if (tid < GRPS*2) {
        int b = (blockIdx.x * PPB_E) / NPB;
        atomicAdd(&stats1[b*16 + tid], lacc[tid]);
    }
}

// ---------------------------------------------------------------- fused GN-apply + FC + next-GN stats
#define PPB_F 16
__global__ __launch_bounds__(256) void k_fc(const float* __restrict__ Vx,
    const float* __restrict__ Vn,                 // nullptr => direct input (no max/min select)
    const float* __restrict__ statsIn, float invcnt,
    const float* __restrict__ gm, const float* __restrict__ bt,
    const float* __restrict__ W,                  // [64][64] row-major (o, m)
    float* __restrict__ outPre, float* __restrict__ statsOut)
{
    __shared__ float wt[CH*CH];                   // wt[m*64+o] = W[o][m]
    __shared__ float affA[CH], affB[CH];
    __shared__ float lacc[GRPS*2];
    int tid = threadIdx.x;
    for (int i = tid; i < CH*CH; i += 256) {
        int m = i >> 6, o = i & 63;
        wt[i] = W[o*CH + m];
    }
    int b = (blockIdx.x * PPB_F) / NPB;
    if (tid < CH) {
        int g = tid >> 3;
        float sv = statsIn[b*16 + g*2 + 0];
        float qv = statsIn[b*16 + g*2 + 1];
        float mean = sv * invcnt;
        float var  = fmaf(-mean, mean, qv * invcnt);
        float rstd = rsqrtf(var + EPSV);
        float a = gm[tid] * rstd;
        affA[tid] = a;
        affB[tid] = fmaf(-mean, a, bt[tid]);
    }
    if (tid < GRPS*2) lacc[tid] = 0.f;
    __syncthreads();
    int lane = tid & 63, w = tid >> 6;
    int p0 = blockIdx.x * PPB_F + w * (PPB_F/4);
    float a = affA[lane], bb = affB[lane];
    bool useMin = (a < 0.f);
    float s = 0.f, ss = 0.f;
    for (int pi = 0; pi < PPB_F/4; ++pi) {
        int p = p0 + pi;
        float x;
        if (Vn) x = useMin ? Vn[p*CH + lane] : Vx[p*CH + lane];
        else    x = Vx[p*CH + lane];
        float z = fmaf(a, x, bb);
        z = (z >= 0.f) ? z : SLOPEV * z;
        float acc = 0.f;
        #pragma unroll
        for (int m = 0; m < CH; ++m)
            acc = fmaf(__shfl(z, m, 64), wt[m*CH + lane], acc);
        outPre[p*CH + lane] = acc;
        s += acc;
        ss = fmaf(acc, acc, ss);
    }
    s  += __shfl_xor(s, 1, 64);  ss += __shfl_xor(ss, 1, 64);
    s  += __shfl_xor(s, 2, 64);  ss += __shfl_xor(ss, 2, 64);
    s  += __shfl_xor(s, 4, 64);  ss += __shfl_xor(ss, 4, 64);
    if ((lane & 7) == 0) {
        atomicAdd(&lacc[(lane>>3)*2 + 0], s);
        atomicAdd(&lacc[(lane>>3)*2 + 1], ss);
    }
    __syncthreads();
    if (tid < GRPS*2)
        atomicAdd(&statsOut[b*16 + tid], lacc[tid]);
}

// ---------------------------------------------------------------- final GN + lrelu -> out
__global__ __launch_bounds__(256) void k_out(const float* __restrict__ Vpre,
    const float* __restrict__ stats, float invcnt,
    const float* __restrict__ gm, const float* __restrict__ bt,
    float* __restrict__ out)
{
    int idx = blockIdx.x * blockDim.x + threadIdx.x;   // one float4 per thread
    int p  = idx >> 4;
    int m0 = (idx & 15) << 2;
    int b  = p >> 13;                                  // p / 8192
    int g  = m0 >> 3;
    float sv = stats[b*16 + g*2 + 0];
    float qv = stats[b*16 + g*2 + 1];
    float mean = sv * invcnt;
    float var  = fmaf(-mean, mean, qv * invcnt);
    float rstd = rsqrtf(var + EPSV);
    float4 v = reinterpret_cast<const float4*>(Vpre)[idx];
    float in[4] = {v.x, v.y, v.z, v.w};
    float r[4];
    #pragma unroll
    for (int j = 0; j < 4; ++j) {
        float aa = gm[m0+j] * rstd;
        float z  = fmaf(aa, in[j] - mean, bt[m0+j]);
        r[j] = (z >= 0.f) ? z : SLOPEV * z;
    }
    float4 o4 = {r[0], r[1], r[2], r[3]};
    reinterpret_cast<float4*>(out)[idx] = o4;
}

// ---------------------------------------------------------------- launch
extern "C" void kernel_launch(void* const* d_in, const int* in_sizes, int n_in,
                              void* d_out, int out_size, void* d_ws, size_t ws_size,
                              hipStream_t stream)
{
    const float* sig = (const float*)d_in[0];
    const void*  edg = d_in[1];
    const float* ef  = (const float*)d_in[2];
    const float* W1  = (const float*)d_in[3];
    const float* g1  = (const float*)d_in[4];
    const float* b1  = (const float*)d_in[5];
    const float* W2  = (const float*)d_in[6];
    const float* g2  = (const float*)d_in[7];
    const float* b2  = (const float*)d_in[8];
    const float* W3  = (const float*)d_in[9];
    const float* g3  = (const float*)d_in[10];
    const float* b3  = (const float*)d_in[11];
    float* out = (float*)d_out;
    float* ws  = (float*)d_ws;

    hipMemsetAsync(d_ws, 0, 1024, stream);   // zero stats + flag
    k_detect<<<128, 256, 0, stream>>>((const unsigned long long*)edg,
                                      (NPTS*KNB)/2, (int*)(ws + WS_FLAG));
    k_y<<<NPTS/64, 256, 0, stream>>>(sig, W1, ws + WS_Y);
    k_edge<<<NPTS/PPB_E, 256, 0, stream>>>(ws + WS_Y, edg, ef, W1,
                                           (const int*)(ws + WS_FLAG),
                                           ws + WS_MX, ws + WS_MN, ws + WS_STATS1);
    k_fc<<<NPTS/PPB_F, 256, 0, stream>>>(ws + WS_MX, ws + WS_MN, ws + WS_STATS1,
                                         1.f/(float)(NPB*KNB*8), g1, b1, W2,
                                         ws + WS_Y, ws + WS_STATS2);
    k_fc<<<NPTS/PPB_F, 256, 0, stream>>>(ws + WS_Y, nullptr, ws + WS_STATS2,
                                         1.f/(float)(NPB*8), g2, b2, W3,
                                         ws + WS_MX, ws + WS_STATS3);
    k_out<<<(NPTS*CH/4)/256, 256, 0, stream>>>(ws + WS_MX, ws + WS_STATS3,
                                         1.f/(float)(NPB*8), g3, b3, out);
}

// Round 3
// 201.971 us; speedup vs baseline: 1.1120x; 1.1120x over previous
//
#include <hip/hip_runtime.h>

#define NB    4
#define NPB   8192
#define NPTS  (NB*NPB)      // 32768
#define KNB   32
#define CH    64
#define W1C   67
#define GRPS  8
#define EPSV  1e-5f
#define SLOPEV 0.1f

typedef float f32x4 __attribute__((ext_vector_type(4)));

// workspace layout (float offsets)
#define WS_STATS1 0
#define WS_STATS2 64
#define WS_STATS3 128
#define WS_FLAG   192          // int flag: 1 => edges are int32
#define WS_Y      256
#define WS_MX     (WS_Y  + NPTS*CH)
#define WS_MN     (WS_MX + NPTS*CH)

// ---------------------------------------------------------------- Y = sig * W1s^T  (+ dtype probe in block 0)
__global__ __launch_bounds__(256) void k_y(const float* __restrict__ sig,
                                           const float* __restrict__ W1,
                                           float* __restrict__ Y,
                                           const int* __restrict__ e_i32,
                                           int* __restrict__ flag)
{
    __shared__ float w1t[CH*CH];          // w1t[c*64+m] = W1[m][c]
    __shared__ int sfnd[4];
    int tid = threadIdx.x;
    if (blockIdx.x == 0) {
        // probe: odd dwords of the first 8192 dwords. int64 => high words all 0.
        int found = 0;
        #pragma unroll
        for (int i = 0; i < 16; ++i) {
            int idx = ((tid << 4) + i) * 2 + 1;
            found |= (e_i32[idx] != 0);
        }
        unsigned long long b = __ballot(found);
        if ((tid & 63) == 0) sfnd[tid >> 6] = (b != 0ull) ? 1 : 0;
    }
    for (int i = tid; i < CH*CH; i += 256) {
        int c = i >> 6, m = i & 63;
        w1t[i] = W1[m*W1C + c];
    }
    __syncthreads();
    if (blockIdx.x == 0 && tid == 0)
        *flag = sfnd[0] | sfnd[1] | sfnd[2] | sfnd[3];
    int lane = tid & 63, w = tid >> 6;
    int p0 = blockIdx.x * 64 + w * 16;    // 16 points per wave, 64 per block
    for (int pi = 0; pi < 16; ++pi) {
        int p = p0 + pi;
        float sv = sig[p*CH + lane];
        float acc = 0.f;
        #pragma unroll
        for (int c = 0; c < CH; ++c)
            acc = fmaf(__shfl(sv, c, 64), w1t[c*CH + lane], acc);
        Y[p*CH + lane] = acc;
    }
}

// ---------------------------------------------------------------- edge pass (4 points/wave, float4 channels)
template<bool IS32>
__device__ __forceinline__ void edge_pass(const float4* __restrict__ Y4,
    const void* __restrict__ edg, const float* __restrict__ ef,
    int p, int il, const float4 yp,
    const float4 we0, const float4 we1, const float4 we2,
    float4& mx, float4& mn, float4& s4, float4& ss4)
{
    const int*       e32 = (const int*)edg;
    const long long* e64 = (const long long*)edg;
    #pragma unroll 8
    for (int k = 0; k < KNB; ++k) {
        int ei = p*KNB + k;
        int e  = IS32 ? __builtin_nontemporal_load(e32 + ei)
                      : (int)__builtin_nontemporal_load(e64 + ei);
        float c0 = __builtin_nontemporal_load(ef + ei*3 + 0);
        float c1 = __builtin_nontemporal_load(ef + ei*3 + 1);
        float c2 = __builtin_nontemporal_load(ef + ei*3 + 2);
        float4 q = Y4[e*16 + il];
        float4 t;
        t.x = fmaf(c2, we2.x, fmaf(c1, we1.x, fmaf(c0, we0.x, q.x - yp.x)));
        t.y = fmaf(c2, we2.y, fmaf(c1, we1.y, fmaf(c0, we0.y, q.y - yp.y)));
        t.z = fmaf(c2, we2.z, fmaf(c1, we1.z, fmaf(c0, we0.z, q.z - yp.z)));
        t.w = fmaf(c2, we2.w, fmaf(c1, we1.w, fmaf(c0, we0.w, q.w - yp.w)));
        mx.x = fmaxf(mx.x, t.x); mx.y = fmaxf(mx.y, t.y); mx.z = fmaxf(mx.z, t.z); mx.w = fmaxf(mx.w, t.w);
        mn.x = fminf(mn.x, t.x); mn.y = fminf(mn.y, t.y); mn.z = fminf(mn.z, t.z); mn.w = fminf(mn.w, t.w);
        s4.x += t.x; s4.y += t.y; s4.z += t.z; s4.w += t.w;
        ss4.x = fmaf(t.x, t.x, ss4.x); ss4.y = fmaf(t.y, t.y, ss4.y);
        ss4.z = fmaf(t.z, t.z, ss4.z); ss4.w = fmaf(t.w, t.w, ss4.w);
    }
}

#define PPB_E 16
__global__ __launch_bounds__(256) void k_edge(const float* __restrict__ Y,
    const void* __restrict__ edg, const float* __restrict__ ef,
    const float* __restrict__ W1, const int* __restrict__ flag,
    float* __restrict__ Mx, float* __restrict__ Mn, float* __restrict__ stats1)
{
    __shared__ float lacc[GRPS*2];
    int tid = threadIdx.x, lane = tid & 63, wv = tid >> 6;
    int il = lane & 15;               // lane within 16-group: channels il*4..il*4+3
    int g16 = lane >> 4;              // which of 4 points this wave handles
    if (tid < GRPS*2) lacc[tid] = 0.f;

    const float4* Y4 = (const float4*)Y;
    int p = blockIdx.x * PPB_E + wv * 4 + g16;

    float4 we0, we1, we2;
    {
        int ch = il << 2;
        we0.x = W1[(ch+0)*W1C + 64]; we0.y = W1[(ch+1)*W1C + 64];
        we0.z = W1[(ch+2)*W1C + 64]; we0.w = W1[(ch+3)*W1C + 64];
        we1.x = W1[(ch+0)*W1C + 65]; we1.y = W1[(ch+1)*W1C + 65];
        we1.z = W1[(ch+2)*W1C + 65]; we1.w = W1[(ch+3)*W1C + 65];
        we2.x = W1[(ch+0)*W1C + 66]; we2.y = W1[(ch+1)*W1C + 66];
        we2.z = W1[(ch+2)*W1C + 66]; we2.w = W1[(ch+3)*W1C + 66];
    }
    float4 yp = Y4[p*16 + il];
    float4 mx = make_float4(-3.4e38f, -3.4e38f, -3.4e38f, -3.4e38f);
    float4 mn = make_float4( 3.4e38f,  3.4e38f,  3.4e38f,  3.4e38f);
    float4 s4 = make_float4(0.f, 0.f, 0.f, 0.f);
    float4 ss4 = make_float4(0.f, 0.f, 0.f, 0.f);
    bool is32 = (*flag != 0);
    __syncthreads();   // lacc init visible before atomics

    if (is32) edge_pass<true >(Y4, edg, ef, p, il, yp, we0, we1, we2, mx, mn, s4, ss4);
    else      edge_pass<false>(Y4, edg, ef, p, il, yp, we0, we1, we2, mx, mn, s4, ss4);

    f32x4 mxv = {mx.x, mx.y, mx.z, mx.w};
    f32x4 mnv = {mn.x, mn.y, mn.z, mn.w};
    __builtin_nontemporal_store(mxv, (f32x4*)Mx + p*16 + il);
    __builtin_nontemporal_store(mnv, (f32x4*)Mn + p*16 + il);

    float s  = (s4.x + s4.y) + (s4.z + s4.w);
    float ss = (ss4.x + ss4.y) + (ss4.z + ss4.w);
    s  += __shfl_xor(s, 1, 64);
    ss += __shfl_xor(ss, 1, 64);
    if ((lane & 1) == 0) {
        int g = il >> 1;              // channel group 0..7
        atomicAdd(&lacc[g*2 + 0], s);
        atomicAdd(&lacc[g*2 + 1], ss);
    }
    __syncthreads();
    if (tid < GRPS*2) {
        int b = (blockIdx.x * PPB_E) / NPB;
        atomicAdd(&stats1[b*16 + tid], lacc[tid]);
    }
}

// ---------------------------------------------------------------- fused GN-apply + FC + next-GN stats
#define PPB_F 16
__global__ __launch_bounds__(256) void k_fc(const float* __restrict__ Vx,
    const float* __restrict__ Vn,                 // nullptr => direct input (no max/min select)
    const float* __restrict__ statsIn, float invcnt,
    const float* __restrict__ gm, const float* __restrict__ bt,
    const float* __restrict__ W,                  // [64][64] row-major (o, m)
    float* __restrict__ outPre, float* __restrict__ statsOut)
{
    __shared__ float wt[CH*CH];                   // wt[m*64+o] = W[o][m]
    __shared__ float affA[CH], affB[CH];
    __shared__ float lacc[GRPS*2];
    int tid = threadIdx.x;
    for (int i = tid; i < CH*CH; i += 256) {
        int m = i >> 6, o = i & 63;
        wt[i] = W[o*CH + m];
    }
    int b = (blockIdx.x * PPB_F) / NPB;
    if (tid < CH) {
        int g = tid >> 3;
        float sv = statsIn[b*16 + g*2 + 0];
        float qv = statsIn[b*16 + g*2 + 1];
        float mean = sv * invcnt;
        float var  = fmaf(-mean, mean, qv * invcnt);
        float rstd = rsqrtf(var + EPSV);
        float a = gm[tid] * rstd;
        affA[tid] = a;
        affB[tid] = fmaf(-mean, a, bt[tid]);
    }
    if (tid < GRPS*2) lacc[tid] = 0.f;
    __syncthreads();
    int lane = tid & 63, w = tid >> 6;
    int p0 = blockIdx.x * PPB_F + w * (PPB_F/4);
    float a = affA[lane], bb = affB[lane];
    bool useMin = (a < 0.f);
    float s = 0.f, ss = 0.f;
    for (int pi = 0; pi < PPB_F/4; ++pi) {
        int p = p0 + pi;
        float x;
        if (Vn) x = useMin ? Vn[p*CH + lane] : Vx[p*CH + lane];
        else    x = Vx[p*CH + lane];
        float z = fmaf(a, x, bb);
        z = (z >= 0.f) ? z : SLOPEV * z;
        float acc = 0.f;
        #pragma unroll
        for (int m = 0; m < CH; ++m)
            acc = fmaf(__shfl(z, m, 64), wt[m*CH + lane], acc);
        outPre[p*CH + lane] = acc;
        s += acc;
        ss = fmaf(acc, acc, ss);
    }
    s  += __shfl_xor(s, 1, 64);  ss += __shfl_xor(ss, 1, 64);
    s  += __shfl_xor(s, 2, 64);  ss += __shfl_xor(ss, 2, 64);
    s  += __shfl_xor(s, 4, 64);  ss += __shfl_xor(ss, 4, 64);
    if ((lane & 7) == 0) {
        atomicAdd(&lacc[(lane>>3)*2 + 0], s);
        atomicAdd(&lacc[(lane>>3)*2 + 1], ss);
    }
    __syncthreads();
    if (tid < GRPS*2)
        atomicAdd(&statsOut[b*16 + tid], lacc[tid]);
}

// ---------------------------------------------------------------- final GN + lrelu -> out
__global__ __launch_bounds__(256) void k_out(const float* __restrict__ Vpre,
    const float* __restrict__ stats, float invcnt,
    const float* __restrict__ gm, const float* __restrict__ bt,
    float* __restrict__ out)
{
    int idx = blockIdx.x * blockDim.x + threadIdx.x;   // one float4 per thread
    int p  = idx >> 4;
    int m0 = (idx & 15) << 2;
    int b  = p >> 13;                                  // p / 8192
    int g  = m0 >> 3;
    float sv = stats[b*16 + g*2 + 0];
    float qv = stats[b*16 + g*2 + 1];
    float mean = sv * invcnt;
    float var  = fmaf(-mean, mean, qv * invcnt);
    float rstd = rsqrtf(var + EPSV);
    float4 v = reinterpret_cast<const float4*>(Vpre)[idx];
    float in[4] = {v.x, v.y, v.z, v.w};
    float r[4];
    #pragma unroll
    for (int j = 0; j < 4; ++j) {
        float aa = gm[m0+j] * rstd;
        float z  = fmaf(aa, in[j] - mean, bt[m0+j]);
        r[j] = (z >= 0.f) ? z : SLOPEV * z;
    }
    float4 o4 = {r[0], r[1], r[2], r[3]};
    reinterpret_cast<float4*>(out)[idx] = o4;
}

// ---------------------------------------------------------------- launch
extern "C" void kernel_launch(void* const* d_in, const int* in_sizes, int n_in,
                              void* d_out, int out_size, void* d_ws, size_t ws_size,
                              hipStream_t stream)
{
    const float* sig = (const float*)d_in[0];
    const void*  edg = d_in[1];
    const float* ef  = (const float*)d_in[2];
    const float* W1  = (const float*)d_in[3];
    const float* g1  = (const float*)d_in[4];
    const float* b1  = (const float*)d_in[5];
    const float* W2  = (const float*)d_in[6];
    const float* g2  = (const float*)d_in[7];
    const float* b2  = (const float*)d_in[8];
    const float* W3  = (const float*)d_in[9];
    const float* g3  = (const float*)d_in[10];
    const float* b3  = (const float*)d_in[11];
    float* out = (float*)d_out;
    float* ws  = (float*)d_ws;

    (void)hipMemsetAsync(d_ws, 0, 1024, stream);   // zero stats + flag
    k_y<<<NPTS/64, 256, 0, stream>>>(sig, W1, ws + WS_Y, (const int*)edg,
                                     (int*)(ws + WS_FLAG));
    k_edge<<<NPTS/PPB_E, 256, 0, stream>>>(ws + WS_Y, edg, ef, W1,
                                           (const int*)(ws + WS_FLAG),
                                           ws + WS_MX, ws + WS_MN, ws + WS_STATS1);
    k_fc<<<NPTS/PPB_F, 256, 0, stream>>>(ws + WS_MX, ws + WS_MN, ws + WS_STATS1,
                                         1.f/(float)(NPB*KNB*8), g1, b1, W2,
                                         ws + WS_Y, ws + WS_STATS2);
    k_fc<<<NPTS/PPB_F, 256, 0, stream>>>(ws + WS_Y, nullptr, ws + WS_STATS2,
                                         1.f/(float)(NPB*8), g2, b2, W3,
                                         ws + WS_MX, ws + WS_STATS3);
    k_out<<<(NPTS*CH/4)/256, 256, 0, stream>>>(ws + WS_MX, ws + WS_STATS3,
                                         1.f/(float)(NPB*8), g3, b3, out);
}

// Round 4
// 81.241 us; speedup vs baseline: 2.7644x; 2.4861x over previous
//
#include <hip/hip_runtime.h>

#define NB    4
#define NPB   8192
#define NPTS  (NB*NPB)      // 32768
#define KNB   32
#define CH    64
#define W1C   67
#define GRPS  8
#define EPSV  1e-5f
#define SLOPEV 0.1f

typedef float f32x4 __attribute__((ext_vector_type(4)));
typedef short bf16x8 __attribute__((ext_vector_type(8)));

// workspace layout (float offsets)
#define WS_STATS1 0
#define WS_STATS2 64
#define WS_STATS3 128
#define WS_FLAG   192          // int flag: 1 => edges are int32
#define WS_Y      256
#define WS_MX     (WS_Y  + NPTS*CH)
#define WS_MN     (WS_MX + NPTS*CH)

#define LDP 72                 // padded LDS row stride (bf16 elems): 2-way bank alias only

__device__ __forceinline__ unsigned short f2bf(float f) {
    unsigned u = __float_as_uint(f);
    u += 0x7fff + ((u >> 16) & 1);          // round-nearest-even
    return (unsigned short)(u >> 16);
}

// ---------------------------------------------------------------- MFMA matmul family
// MODE 0: Y = sig * W1s^T   (+ edge-dtype probe in block 0; no affine, no stats)
// MODE 1: FC2: in = GN1-apply(lrelu) of max/min-selected Mx/Mn; out = in*W2^T; stats2
// MODE 2: FC3: in = GN2-apply(lrelu) of z2pre;                 out = in*W3^T; stats3
template<int MODE>
__global__ __launch_bounds__(256) void k_mm(
    const float* __restrict__ X0,   // sig / Mx / z2pre
    const float* __restrict__ X1,   // -   / Mn / -
    const float* __restrict__ Wg,   // W1  / W2 / W3
    const float* __restrict__ statsIn, float invcnt,
    const float* __restrict__ gm, const float* __restrict__ bt,
    float* __restrict__ Out,
    float* __restrict__ statsOut,
    const int* __restrict__ e_i32, int* __restrict__ flag)
{
    __shared__ unsigned short Al[128*LDP];
    __shared__ unsigned short Wl[64*LDP];
    __shared__ float affA[64], affB[64];
    __shared__ float lacc[16];
    __shared__ int sfnd[4];
    int tid = threadIdx.x;
    int pbase = blockIdx.x * 128;
    int b = pbase >> 13;                      // batch index (NPB = 8192)

    if (MODE == 0 && blockIdx.x == 0) {
        // probe: odd dwords of the first 8192 dwords. int64 => high words all 0.
        int found = 0;
        #pragma unroll
        for (int i = 0; i < 16; ++i) {
            int idx = ((tid << 4) + i) * 2 + 1;
            found |= (e_i32[idx] != 0);
        }
        unsigned long long bl = __ballot(found);
        if ((tid & 63) == 0) sfnd[tid >> 6] = (bl != 0ull) ? 1 : 0;
    }
    if (MODE != 0) {
        if (tid < 64) {
            int g = tid >> 3;
            float sv = statsIn[b*16 + g*2 + 0];
            float qv = statsIn[b*16 + g*2 + 1];
            float mean = sv * invcnt;
            float var  = fmaf(-mean, mean, qv * invcnt);
            float rstd = rsqrtf(var + EPSV);
            float a = gm[tid] * rstd;
            affA[tid] = a;
            affB[tid] = fmaf(-mean, a, bt[tid]);
        }
    }
    if (tid < 16) lacc[tid] = 0.f;
    __syncthreads();
    if (MODE == 0 && blockIdx.x == 0 && tid == 0)
        *flag = sfnd[0] | sfnd[1] | sfnd[2] | sfnd[3];

    // ---- stage W (bf16): Wl[o][m] = W[o][m]  (B-fragment-ready: row = out-ch)
    {
        const int wstride = (MODE == 0) ? W1C : 64;
        #pragma unroll
        for (int i = 0; i < 16; ++i) {
            int e = tid + 256*i;
            int o = e >> 6, m = e & 63;
            Wl[o*LDP + m] = f2bf(Wg[o*wstride + m]);
        }
    }
    // ---- stage A (bf16): activated input rows
    #pragma unroll
    for (int it = 0; it < 8; ++it) {
        int fi = it*1024 + tid*4;
        int p = fi >> 6;                      // 0..127
        int m = fi & 63;
        float xv[4];
        if (MODE == 1) {
            f32x4 vx = *(const f32x4*)&X0[(pbase+p)*64 + m];
            f32x4 vn = *(const f32x4*)&X1[(pbase+p)*64 + m];
            #pragma unroll
            for (int j = 0; j < 4; ++j) {
                float a = affA[m+j];
                float x = (a < 0.f) ? vn[j] : vx[j];
                float z = fmaf(a, x, affB[m+j]);
                xv[j] = (z >= 0.f) ? z : SLOPEV * z;
            }
        } else if (MODE == 2) {
            f32x4 vx = *(const f32x4*)&X0[(pbase+p)*64 + m];
            #pragma unroll
            for (int j = 0; j < 4; ++j) {
                float z = fmaf(affA[m+j], vx[j], affB[m+j]);
                xv[j] = (z >= 0.f) ? z : SLOPEV * z;
            }
        } else {
            f32x4 vx = *(const f32x4*)&X0[(pbase+p)*64 + m];
            #pragma unroll
            for (int j = 0; j < 4; ++j) xv[j] = vx[j];
        }
        #pragma unroll
        for (int j = 0; j < 4; ++j)
            Al[p*LDP + m + j] = f2bf(xv[j]);
    }
    __syncthreads();

    // ---- fragments + MFMA: wave w owns points [w*32, w*32+32), all 64 outputs
    int l = tid & 63, w = tid >> 6;
    int lr = l & 15;                          // row/col within tile
    int lk = l >> 4;                          // k-group (0..3)
    bf16x8 af[2][2], bw[4][2];
    #pragma unroll
    for (int pt = 0; pt < 2; ++pt)
        #pragma unroll
        for (int kh = 0; kh < 2; ++kh)
            af[pt][kh] = *(const bf16x8*)&Al[(w*32 + pt*16 + lr)*LDP + kh*32 + lk*8];
    #pragma unroll
    for (int ot = 0; ot < 4; ++ot)
        #pragma unroll
        for (int kh = 0; kh < 2; ++kh)
            bw[ot][kh] = *(const bf16x8*)&Wl[(ot*16 + lr)*LDP + kh*32 + lk*8];

    f32x4 acc[2][4];
    #pragma unroll
    for (int pt = 0; pt < 2; ++pt)
        #pragma unroll
        for (int ot = 0; ot < 4; ++ot) {
            f32x4 c = {0.f, 0.f, 0.f, 0.f};
            c = __builtin_amdgcn_mfma_f32_16x16x32_bf16(af[pt][0], bw[ot][0], c, 0, 0, 0);
            c = __builtin_amdgcn_mfma_f32_16x16x32_bf16(af[pt][1], bw[ot][1], c, 0, 0, 0);
            acc[pt][ot] = c;
        }

    // ---- store C: row = lk*4 + r, col = lr  (m89-verified layout)
    #pragma unroll
    for (int pt = 0; pt < 2; ++pt)
        #pragma unroll
        for (int ot = 0; ot < 4; ++ot)
            #pragma unroll
            for (int r = 0; r < 4; ++r) {
                int p = pbase + w*32 + pt*16 + lk*4 + r;
                int o = ot*16 + lr;
                Out[p*64 + o] = acc[pt][ot][r];
            }

    // ---- fused next-GN stats
    if (MODE != 0) {
        #pragma unroll
        for (int ot = 0; ot < 4; ++ot) {
            float s = 0.f, ss = 0.f;
            #pragma unroll
            for (int pt = 0; pt < 2; ++pt)
                #pragma unroll
                for (int r = 0; r < 4; ++r) {
                    float v = acc[pt][ot][r];
                    s += v;
                    ss = fmaf(v, v, ss);
                }
            // reduce across lanes sharing the same output channel (l, l^16, l^32, l^48)
            s += __shfl_xor(s, 16, 64);  ss += __shfl_xor(ss, 16, 64);
            s += __shfl_xor(s, 32, 64);  ss += __shfl_xor(ss, 32, 64);
            // reduce the 8 channels of each group
            s += __shfl_xor(s, 1, 64);   ss += __shfl_xor(ss, 1, 64);
            s += __shfl_xor(s, 2, 64);   ss += __shfl_xor(ss, 2, 64);
            s += __shfl_xor(s, 4, 64);   ss += __shfl_xor(ss, 4, 64);
            if ((l & 7) == 0 && l < 16) {
                int g = ot*2 + (l >> 3);
                atomicAdd(&lacc[g*2 + 0], s);
                atomicAdd(&lacc[g*2 + 1], ss);
            }
        }
        __syncthreads();
        if (tid < 16)
            atomicAdd(&statsOut[b*16 + tid], lacc[tid]);
    }
}

// ---------------------------------------------------------------- edge pass (4 points/wave, float4 channels)
template<bool IS32>
__device__ __forceinline__ void edge_pass(const float4* __restrict__ Y4,
    const void* __restrict__ edg, const float* __restrict__ ef,
    int p, int il, const float4 yp,
    const float4 we0, const float4 we1, const float4 we2,
    float4& mx, float4& mn, float4& s4, float4& ss4)
{
    const int*       e32 = (const int*)edg;
    const long long* e64 = (const long long*)edg;
    #pragma unroll 8
    for (int k = 0; k < KNB; ++k) {
        int ei = p*KNB + k;
        int e  = IS32 ? __builtin_nontemporal_load(e32 + ei)
                      : (int)__builtin_nontemporal_load(e64 + ei);
        float c0 = __builtin_nontemporal_load(ef + ei*3 + 0);
        float c1 = __builtin_nontemporal_load(ef + ei*3 + 1);
        float c2 = __builtin_nontemporal_load(ef + ei*3 + 2);
        float4 q = Y4[e*16 + il];
        float4 t;
        t.x = fmaf(c2, we2.x, fmaf(c1, we1.x, fmaf(c0, we0.x, q.x - yp.x)));
        t.y = fmaf(c2, we2.y, fmaf(c1, we1.y, fmaf(c0, we0.y, q.y - yp.y)));
        t.z = fmaf(c2, we2.z, fmaf(c1, we1.z, fmaf(c0, we0.z, q.z - yp.z)));
        t.w = fmaf(c2, we2.w, fmaf(c1, we1.w, fmaf(c0, we0.w, q.w - yp.w)));
        mx.x = fmaxf(mx.x, t.x); mx.y = fmaxf(mx.y, t.y); mx.z = fmaxf(mx.z, t.z); mx.w = fmaxf(mx.w, t.w);
        mn.x = fminf(mn.x, t.x); mn.y = fminf(mn.y, t.y); mn.z = fminf(mn.z, t.z); mn.w = fminf(mn.w, t.w);
        s4.x += t.x; s4.y += t.y; s4.z += t.z; s4.w += t.w;
        ss4.x = fmaf(t.x, t.x, ss4.x); ss4.y = fmaf(t.y, t.y, ss4.y);
        ss4.z = fmaf(t.z, t.z, ss4.z); ss4.w = fmaf(t.w, t.w, ss4.w);
    }
}

#define PPB_E 16
__global__ __launch_bounds__(256) void k_edge(const float* __restrict__ Y,
    const void* __restrict__ edg, const float* __restrict__ ef,
    const float* __restrict__ W1, const int* __restrict__ flag,
    float* __restrict__ Mx, float* __restrict__ Mn, float* __restrict__ stats1)
{
    __shared__ float lacc[GRPS*2];
    int tid = threadIdx.x, lane = tid & 63, wv = tid >> 6;
    int il = lane & 15;               // lane within 16-group: channels il*4..il*4+3
    int g16 = lane >> 4;              // which of 4 points this wave handles
    if (tid < GRPS*2) lacc[tid] = 0.f;

    const float4* Y4 = (const float4*)Y;
    int p = blockIdx.x * PPB_E + wv * 4 + g16;

    float4 we0, we1, we2;
    {
        int ch = il << 2;
        we0.x = W1[(ch+0)*W1C + 64]; we0.y = W1[(ch+1)*W1C + 64];
        we0.z = W1[(ch+2)*W1C + 64]; we0.w = W1[(ch+3)*W1C + 64];
        we1.x = W1[(ch+0)*W1C + 65]; we1.y = W1[(ch+1)*W1C + 65];
        we1.z = W1[(ch+2)*W1C + 65]; we1.w = W1[(ch+3)*W1C + 65];
        we2.x = W1[(ch+0)*W1C + 66]; we2.y = W1[(ch+1)*W1C + 66];
        we2.z = W1[(ch+2)*W1C + 66]; we2.w = W1[(ch+3)*W1C + 66];
    }
    float4 yp = Y4[p*16 + il];
    float4 mx = make_float4(-3.4e38f, -3.4e38f, -3.4e38f, -3.4e38f);
    float4 mn = make_float4( 3.4e38f,  3.4e38f,  3.4e38f,  3.4e38f);
    float4 s4 = make_float4(0.f, 0.f, 0.f, 0.f);
    float4 ss4 = make_float4(0.f, 0.f, 0.f, 0.f);
    bool is32 = (*flag != 0);
    __syncthreads();   // lacc init visible before atomics

    if (is32) edge_pass<true >(Y4, edg, ef, p, il, yp, we0, we1, we2, mx, mn, s4, ss4);
    else      edge_pass<false>(Y4, edg, ef, p, il, yp, we0, we1, we2, mx, mn, s4, ss4);

    f32x4 mxv = {mx.x, mx.y, mx.z, mx.w};
    f32x4 mnv = {mn.x, mn.y, mn.z, mn.w};
    __builtin_nontemporal_store(mxv, (f32x4*)Mx + p*16 + il);
    __builtin_nontemporal_store(mnv, (f32x4*)Mn + p*16 + il);

    float s  = (s4.x + s4.y) + (s4.z + s4.w);
    float ss = (ss4.x + ss4.y) + (ss4.z + ss4.w);
    s  += __shfl_xor(s, 1, 64);
    ss += __shfl_xor(ss, 1, 64);
    if ((lane & 1) == 0) {
        int g = il >> 1;              // channel group 0..7
        atomicAdd(&lacc[g*2 + 0], s);
        atomicAdd(&lacc[g*2 + 1], ss);
    }
    __syncthreads();
    if (tid < GRPS*2) {
        int b = (blockIdx.x * PPB_E) / NPB;
        atomicAdd(&stats1[b*16 + tid], lacc[tid]);
    }
}

// ---------------------------------------------------------------- final GN + lrelu -> out
__global__ __launch_bounds__(256) void k_out(const float* __restrict__ Vpre,
    const float* __restrict__ stats, float invcnt,
    const float* __restrict__ gm, const float* __restrict__ bt,
    float* __restrict__ out)
{
    int idx = blockIdx.x * blockDim.x + threadIdx.x;   // one float4 per thread
    int p  = idx >> 4;
    int m0 = (idx & 15) << 2;
    int b  = p >> 13;                                  // p / 8192
    int g  = m0 >> 3;
    float sv = stats[b*16 + g*2 + 0];
    float qv = stats[b*16 + g*2 + 1];
    float mean = sv * invcnt;
    float var  = fmaf(-mean, mean, qv * invcnt);
    float rstd = rsqrtf(var + EPSV);
    float4 v = reinterpret_cast<const float4*>(Vpre)[idx];
    float in[4] = {v.x, v.y, v.z, v.w};
    float r[4];
    #pragma unroll
    for (int j = 0; j < 4; ++j) {
        float aa = gm[m0+j] * rstd;
        float z  = fmaf(aa, in[j] - mean, bt[m0+j]);
        r[j] = (z >= 0.f) ? z : SLOPEV * z;
    }
    float4 o4 = {r[0], r[1], r[2], r[3]};
    reinterpret_cast<float4*>(out)[idx] = o4;
}

// ---------------------------------------------------------------- launch
extern "C" void kernel_launch(void* const* d_in, const int* in_sizes, int n_in,
                              void* d_out, int out_size, void* d_ws, size_t ws_size,
                              hipStream_t stream)
{
    const float* sig = (const float*)d_in[0];
    const void*  edg = d_in[1];
    const float* ef  = (const float*)d_in[2];
    const float* W1  = (const float*)d_in[3];
    const float* g1  = (const float*)d_in[4];
    const float* b1  = (const float*)d_in[5];
    const float* W2  = (const float*)d_in[6];
    const float* g2  = (const float*)d_in[7];
    const float* b2  = (const float*)d_in[8];
    const float* W3  = (const float*)d_in[9];
    const float* g3  = (const float*)d_in[10];
    const float* b3  = (const float*)d_in[11];
    float* out = (float*)d_out;
    float* ws  = (float*)d_ws;

    (void)hipMemsetAsync(d_ws, 0, 1024, stream);   // zero stats + flag
    k_mm<0><<<NPTS/128, 256, 0, stream>>>(sig, nullptr, W1, nullptr, 0.f,
                                          nullptr, nullptr, ws + WS_Y, nullptr,
                                          (const int*)edg, (int*)(ws + WS_FLAG));
    k_edge<<<NPTS/PPB_E, 256, 0, stream>>>(ws + WS_Y, edg, ef, W1,
                                           (const int*)(ws + WS_FLAG),
                                           ws + WS_MX, ws + WS_MN, ws + WS_STATS1);
    k_mm<1><<<NPTS/128, 256, 0, stream>>>(ws + WS_MX, ws + WS_MN, W2,
                                          ws + WS_STATS1, 1.f/(float)(NPB*KNB*8),
                                          g1, b1, ws + WS_Y, ws + WS_STATS2,
                                          nullptr, nullptr);
    k_mm<2><<<NPTS/128, 256, 0, stream>>>(ws + WS_Y, nullptr, W3,
                                          ws + WS_STATS2, 1.f/(float)(NPB*8),
                                          g2, b2, ws + WS_MX, ws + WS_STATS3,
                                          nullptr, nullptr);
    k_out<<<(NPTS*CH/4)/256, 256, 0, stream>>>(ws + WS_MX, ws + WS_STATS3,
                                         1.f/(float)(NPB*8), g3, b3, out);
}

// Round 5
// 73.823 us; speedup vs baseline: 3.0422x; 1.1005x over previous
//
#include <hip/hip_runtime.h>

#define NB    4
#define NPB   8192
#define NPTS  (NB*NPB)      // 32768
#define KNB   32
#define CH    64
#define W1C   67
#define GRPS  8
#define EPSV  1e-5f
#define SLOPEV 0.1f

typedef float f32x4 __attribute__((ext_vector_type(4)));
typedef short bf16x8 __attribute__((ext_vector_type(8)));
typedef unsigned short u16;
typedef u16 u16x4 __attribute__((ext_vector_type(4)));

// workspace layout (float offsets)
#define WS_STATS1 0
#define WS_STATS2 64
#define WS_STATS3 128
#define WS_FLAG   192          // int flag: 1 => edges are int32
#define WS_YB     256                       // bf16 Y (and later bf16 z2pre): NPTS*CH/2 floats
#define WS_MX     (WS_YB + NPTS*CH/2)       // f32 Mx; later f32 z3pre
#define WS_MN     (WS_MX + NPTS*CH)         // f32 Mn
// total: 256 + 1M + 2M + 2M floats ~= 21 MB

#define LDP 72                 // padded LDS row stride (bf16 elems)

__device__ __forceinline__ u16 f2bf(float f) {
    unsigned u = __float_as_uint(f);
    u += 0x7fff + ((u >> 16) & 1);          // round-nearest-even
    return (u16)(u >> 16);
}
__device__ __forceinline__ float bf2f(u16 h) {
    return __uint_as_float(((unsigned)h) << 16);
}

// ---------------------------------------------------------------- MFMA matmul family
// MODE 0: YB(bf16) = sig * W1s^T   (+ edge-dtype probe in block 0)
// MODE 1: Z2B(bf16) = GN1(lrelu,max/min-select) * W2^T; stats2   (X0=Mx f32, X1=Mn f32)
// MODE 2: Z3(f32)   = GN2(lrelu) * W3^T; stats3                  (X0=Z2B bf16)
template<int MODE>
__global__ __launch_bounds__(256) void k_mm(
    const void* __restrict__ X0,
    const float* __restrict__ X1,
    const float* __restrict__ Wg,
    const float* __restrict__ statsIn, float invcnt,
    const float* __restrict__ gm, const float* __restrict__ bt,
    void* __restrict__ Out,
    float* __restrict__ statsOut,
    const int* __restrict__ e_i32, int* __restrict__ flag)
{
    __shared__ u16 Al[128*LDP];
    __shared__ u16 Wl[64*LDP];
    __shared__ float affA[64], affB[64];
    __shared__ float lacc[16];
    __shared__ int sfnd[4];
    int tid = threadIdx.x;
    int pbase = blockIdx.x * 128;
    int b = pbase >> 13;                      // batch index (NPB = 8192)

    if (MODE == 0 && blockIdx.x == 0) {
        // probe: odd dwords of the first 8192 dwords. int64 => high words all 0.
        int found = 0;
        #pragma unroll
        for (int i = 0; i < 16; ++i) {
            int idx = ((tid << 4) + i) * 2 + 1;
            found |= (e_i32[idx] != 0);
        }
        unsigned long long bl = __ballot(found);
        if ((tid & 63) == 0) sfnd[tid >> 6] = (bl != 0ull) ? 1 : 0;
    }
    if (MODE != 0) {
        if (tid < 64) {
            int g = tid >> 3;
            float sv = statsIn[b*16 + g*2 + 0];
            float qv = statsIn[b*16 + g*2 + 1];
            float mean = sv * invcnt;
            float var  = fmaf(-mean, mean, qv * invcnt);
            float rstd = rsqrtf(var + EPSV);
            float a = gm[tid] * rstd;
            affA[tid] = a;
            affB[tid] = fmaf(-mean, a, bt[tid]);
        }
    }
    if (tid < 16) lacc[tid] = 0.f;
    __syncthreads();
    if (MODE == 0 && blockIdx.x == 0 && tid == 0)
        *flag = sfnd[0] | sfnd[1] | sfnd[2] | sfnd[3];

    // ---- stage W (bf16): Wl[o][m] = W[o][m]
    {
        const int wstride = (MODE == 0) ? W1C : 64;
        #pragma unroll
        for (int i = 0; i < 16; ++i) {
            int e = tid + 256*i;
            int o = e >> 6, m = e & 63;
            Wl[o*LDP + m] = f2bf(Wg[o*wstride + m]);
        }
    }
    // ---- stage A (bf16): activated input rows
    #pragma unroll
    for (int it = 0; it < 8; ++it) {
        int fi = it*1024 + tid*4;
        int p = fi >> 6;                      // 0..127
        int m = fi & 63;
        float xv[4];
        if (MODE == 1) {
            f32x4 vx = *(const f32x4*)&((const float*)X0)[(pbase+p)*64 + m];
            f32x4 vn = *(const f32x4*)&X1[(pbase+p)*64 + m];
            #pragma unroll
            for (int j = 0; j < 4; ++j) {
                float a = affA[m+j];
                float x = (a < 0.f) ? vn[j] : vx[j];
                float z = fmaf(a, x, affB[m+j]);
                xv[j] = (z >= 0.f) ? z : SLOPEV * z;
            }
        } else if (MODE == 2) {
            u16x4 vh = *(const u16x4*)&((const u16*)X0)[(pbase+p)*64 + m];
            #pragma unroll
            for (int j = 0; j < 4; ++j) {
                float z = fmaf(affA[m+j], bf2f(vh[j]), affB[m+j]);
                xv[j] = (z >= 0.f) ? z : SLOPEV * z;
            }
        } else {
            f32x4 vx = *(const f32x4*)&((const float*)X0)[(pbase+p)*64 + m];
            #pragma unroll
            for (int j = 0; j < 4; ++j) xv[j] = vx[j];
        }
        #pragma unroll
        for (int j = 0; j < 4; ++j)
            Al[p*LDP + m + j] = f2bf(xv[j]);
    }
    __syncthreads();

    // ---- fragments + MFMA: wave w owns points [w*32, w*32+32), all 64 outputs
    int l = tid & 63, w = tid >> 6;
    int lr = l & 15;                          // row/col within tile
    int lk = l >> 4;                          // k-group (0..3)
    bf16x8 af[2][2], bw[4][2];
    #pragma unroll
    for (int pt = 0; pt < 2; ++pt)
        #pragma unroll
        for (int kh = 0; kh < 2; ++kh)
            af[pt][kh] = *(const bf16x8*)&Al[(w*32 + pt*16 + lr)*LDP + kh*32 + lk*8];
    #pragma unroll
    for (int ot = 0; ot < 4; ++ot)
        #pragma unroll
        for (int kh = 0; kh < 2; ++kh)
            bw[ot][kh] = *(const bf16x8*)&Wl[(ot*16 + lr)*LDP + kh*32 + lk*8];

    f32x4 acc[2][4];
    #pragma unroll
    for (int pt = 0; pt < 2; ++pt)
        #pragma unroll
        for (int ot = 0; ot < 4; ++ot) {
            f32x4 c = {0.f, 0.f, 0.f, 0.f};
            c = __builtin_amdgcn_mfma_f32_16x16x32_bf16(af[pt][0], bw[ot][0], c, 0, 0, 0);
            c = __builtin_amdgcn_mfma_f32_16x16x32_bf16(af[pt][1], bw[ot][1], c, 0, 0, 0);
            acc[pt][ot] = c;
        }

    // ---- store C: row = lk*4 + r, col = lr
    #pragma unroll
    for (int pt = 0; pt < 2; ++pt)
        #pragma unroll
        for (int ot = 0; ot < 4; ++ot)
            #pragma unroll
            for (int r = 0; r < 4; ++r) {
                int p = pbase + w*32 + pt*16 + lk*4 + r;
                int o = ot*16 + lr;
                if (MODE == 2) ((float*)Out)[p*64 + o] = acc[pt][ot][r];
                else           ((u16*)Out)[p*64 + o]  = f2bf(acc[pt][ot][r]);
            }

    // ---- fused next-GN stats
    if (MODE != 0) {
        #pragma unroll
        for (int ot = 0; ot < 4; ++ot) {
            float s = 0.f, ss = 0.f;
            #pragma unroll
            for (int pt = 0; pt < 2; ++pt)
                #pragma unroll
                for (int r = 0; r < 4; ++r) {
                    float v = acc[pt][ot][r];
                    s += v;
                    ss = fmaf(v, v, ss);
                }
            s += __shfl_xor(s, 16, 64);  ss += __shfl_xor(ss, 16, 64);
            s += __shfl_xor(s, 32, 64);  ss += __shfl_xor(ss, 32, 64);
            s += __shfl_xor(s, 1, 64);   ss += __shfl_xor(ss, 1, 64);
            s += __shfl_xor(s, 2, 64);   ss += __shfl_xor(ss, 2, 64);
            s += __shfl_xor(s, 4, 64);   ss += __shfl_xor(ss, 4, 64);
            if ((l & 7) == 0 && l < 16) {
                int g = ot*2 + (l >> 3);
                atomicAdd(&lacc[g*2 + 0], s);
                atomicAdd(&lacc[g*2 + 1], ss);
            }
        }
        __syncthreads();
        if (tid < 16)
            atomicAdd(&statsOut[b*16 + tid], lacc[tid]);
    }
}

// ---------------------------------------------------------------- edge pass (4 points/wave, bf16 gathers)
template<bool IS32>
__device__ __forceinline__ void edge_pass(const u16x4* __restrict__ Y4,
    const void* __restrict__ edg, const float* __restrict__ ef,
    int p, int il, const float4 yp,
    const float4 we0, const float4 we1, const float4 we2,
    float4& mx, float4& mn, float4& s4, float4& ss4)
{
    const int*       e32 = (const int*)edg;
    const long long* e64 = (const long long*)edg;
    #pragma unroll 8
    for (int k = 0; k < KNB; ++k) {
        int ei = p*KNB + k;
        int e  = IS32 ? __builtin_nontemporal_load(e32 + ei)
                      : (int)__builtin_nontemporal_load(e64 + ei);
        float c0 = __builtin_nontemporal_load(ef + ei*3 + 0);
        float c1 = __builtin_nontemporal_load(ef + ei*3 + 1);
        float c2 = __builtin_nontemporal_load(ef + ei*3 + 2);
        u16x4 qh = Y4[e*16 + il];
        float4 t;
        t.x = fmaf(c2, we2.x, fmaf(c1, we1.x, fmaf(c0, we0.x, bf2f(qh[0]) - yp.x)));
        t.y = fmaf(c2, we2.y, fmaf(c1, we1.y, fmaf(c0, we0.y, bf2f(qh[1]) - yp.y)));
        t.z = fmaf(c2, we2.z, fmaf(c1, we1.z, fmaf(c0, we0.z, bf2f(qh[2]) - yp.z)));
        t.w = fmaf(c2, we2.w, fmaf(c1, we1.w, fmaf(c0, we0.w, bf2f(qh[3]) - yp.w)));
        mx.x = fmaxf(mx.x, t.x); mx.y = fmaxf(mx.y, t.y); mx.z = fmaxf(mx.z, t.z); mx.w = fmaxf(mx.w, t.w);
        mn.x = fminf(mn.x, t.x); mn.y = fminf(mn.y, t.y); mn.z = fminf(mn.z, t.z); mn.w = fminf(mn.w, t.w);
        s4.x += t.x; s4.y += t.y; s4.z += t.z; s4.w += t.w;
        ss4.x = fmaf(t.x, t.x, ss4.x); ss4.y = fmaf(t.y, t.y, ss4.y);
        ss4.z = fmaf(t.z, t.z, ss4.z); ss4.w = fmaf(t.w, t.w, ss4.w);
    }
}

#define PPB_E 16
__global__ __launch_bounds__(256) void k_edge(const u16* __restrict__ Yb,
    const void* __restrict__ edg, const float* __restrict__ ef,
    const float* __restrict__ W1, const int* __restrict__ flag,
    float* __restrict__ Mx, float* __restrict__ Mn, float* __restrict__ stats1)
{
    __shared__ float lacc[GRPS*2];
    int tid = threadIdx.x, lane = tid & 63, wv = tid >> 6;
    int il = lane & 15;               // lane within 16-group: channels il*4..il*4+3
    int g16 = lane >> 4;              // which of 4 points this wave handles
    if (tid < GRPS*2) lacc[tid] = 0.f;

    const u16x4* Y4 = (const u16x4*)Yb;
    int p = blockIdx.x * PPB_E + wv * 4 + g16;

    float4 we0, we1, we2;
    {
        int ch = il << 2;
        we0.x = W1[(ch+0)*W1C + 64]; we0.y = W1[(ch+1)*W1C + 64];
        we0.z = W1[(ch+2)*W1C + 64]; we0.w = W1[(ch+3)*W1C + 64];
        we1.x = W1[(ch+0)*W1C + 65]; we1.y = W1[(ch+1)*W1C + 65];
        we1.z = W1[(ch+2)*W1C + 65]; we1.w = W1[(ch+3)*W1C + 65];
        we2.x = W1[(ch+0)*W1C + 66]; we2.y = W1[(ch+1)*W1C + 66];
        we2.z = W1[(ch+2)*W1C + 66]; we2.w = W1[(ch+3)*W1C + 66];
    }
    u16x4 yh = Y4[p*16 + il];
    float4 yp = make_float4(bf2f(yh[0]), bf2f(yh[1]), bf2f(yh[2]), bf2f(yh[3]));
    float4 mx = make_float4(-3.4e38f, -3.4e38f, -3.4e38f, -3.4e38f);
    float4 mn = make_float4( 3.4e38f,  3.4e38f,  3.4e38f,  3.4e38f);
    float4 s4 = make_float4(0.f, 0.f, 0.f, 0.f);
    float4 ss4 = make_float4(0.f, 0.f, 0.f, 0.f);
    bool is32 = (*flag != 0);
    __syncthreads();   // lacc init visible before atomics

    if (is32) edge_pass<true >(Y4, edg, ef, p, il, yp, we0, we1, we2, mx, mn, s4, ss4);
    else      edge_pass<false>(Y4, edg, ef, p, il, yp, we0, we1, we2, mx, mn, s4, ss4);

    f32x4 mxv = {mx.x, mx.y, mx.z, mx.w};
    f32x4 mnv = {mn.x, mn.y, mn.z, mn.w};
    __builtin_nontemporal_store(mxv, (f32x4*)Mx + p*16 + il);
    __builtin_nontemporal_store(mnv, (f32x4*)Mn + p*16 + il);

    float s  = (s4.x + s4.y) + (s4.z + s4.w);
    float ss = (ss4.x + ss4.y) + (ss4.z + ss4.w);
    s  += __shfl_xor(s, 1, 64);
    ss += __shfl_xor(ss, 1, 64);
    if ((lane & 1) == 0) {
        int g = il >> 1;              // channel group 0..7
        atomicAdd(&lacc[g*2 + 0], s);
        atomicAdd(&lacc[g*2 + 1], ss);
    }
    __syncthreads();
    if (tid < GRPS*2) {
        int b = (blockIdx.x * PPB_E) / NPB;
        atomicAdd(&stats1[b*16 + tid], lacc[tid]);
    }
}

// ---------------------------------------------------------------- final GN + lrelu -> out
__global__ __launch_bounds__(256) void k_out(const float* __restrict__ Vpre,
    const float* __restrict__ stats, float invcnt,
    const float* __restrict__ gm, const float* __restrict__ bt,
    float* __restrict__ out)
{
    int idx = blockIdx.x * blockDim.x + threadIdx.x;   // one float4 per thread
    int p  = idx >> 4;
    int m0 = (idx & 15) << 2;
    int b  = p >> 13;                                  // p / 8192
    int g  = m0 >> 3;
    float sv = stats[b*16 + g*2 + 0];
    float qv = stats[b*16 + g*2 + 1];
    float mean = sv * invcnt;
    float var  = fmaf(-mean, mean, qv * invcnt);
    float rstd = rsqrtf(var + EPSV);
    float4 v = reinterpret_cast<const float4*>(Vpre)[idx];
    float in[4] = {v.x, v.y, v.z, v.w};
    float r[4];
    #pragma unroll
    for (int j = 0; j < 4; ++j) {
        float aa = gm[m0+j] * rstd;
        float z  = fmaf(aa, in[j] - mean, bt[m0+j]);
        r[j] = (z >= 0.f) ? z : SLOPEV * z;
    }
    float4 o4 = {r[0], r[1], r[2], r[3]};
    reinterpret_cast<float4*>(out)[idx] = o4;
}

// ---------------------------------------------------------------- launch
extern "C" void kernel_launch(void* const* d_in, const int* in_sizes, int n_in,
                              void* d_out, int out_size, void* d_ws, size_t ws_size,
                              hipStream_t stream)
{
    const float* sig = (const float*)d_in[0];
    const void*  edg = d_in[1];
    const float* ef  = (const float*)d_in[2];
    const float* W1  = (const float*)d_in[3];
    const float* g1  = (const float*)d_in[4];
    const float* b1  = (const float*)d_in[5];
    const float* W2  = (const float*)d_in[6];
    const float* g2  = (const float*)d_in[7];
    const float* b2  = (const float*)d_in[8];
    const float* W3  = (const float*)d_in[9];
    const float* g3  = (const float*)d_in[10];
    const float* b3  = (const float*)d_in[11];
    float* out = (float*)d_out;
    float* ws  = (float*)d_ws;
    u16*   yb  = (u16*)(ws + WS_YB);

    (void)hipMemsetAsync(d_ws, 0, 1024, stream);   // zero stats + flag
    k_mm<0><<<NPTS/128, 256, 0, stream>>>(sig, nullptr, W1, nullptr, 0.f,
                                          nullptr, nullptr, yb, nullptr,
                                          (const int*)edg, (int*)(ws + WS_FLAG));
    k_edge<<<NPTS/PPB_E, 256, 0, stream>>>(yb, edg, ef, W1,
                                           (const int*)(ws + WS_FLAG),
                                           ws + WS_MX, ws + WS_MN, ws + WS_STATS1);
    k_mm<1><<<NPTS/128, 256, 0, stream>>>(ws + WS_MX, ws + WS_MN, W2,
                                          ws + WS_STATS1, 1.f/(float)(NPB*KNB*8),
                                          g1, b1, yb, ws + WS_STATS2,
                                          nullptr, nullptr);
    k_mm<2><<<NPTS/128, 256, 0, stream>>>(yb, nullptr, W3,
                                          ws + WS_STATS2, 1.f/(float)(NPB*8),
                                          g2, b2, ws + WS_MX, ws + WS_STATS3,
                                          nullptr, nullptr);
    k_out<<<(NPTS*CH/4)/256, 256, 0, stream>>>(ws + WS_MX, ws + WS_STATS3,
                                         1.f/(float)(NPB*8), g3, b3, out);
}

// Round 6
// 63.941 us; speedup vs baseline: 3.5123x; 1.1545x over previous
//
#include <hip/hip_runtime.h>

#define NB    4
#define NPB   8192
#define NPTS  (NB*NPB)      // 32768
#define KNB   32
#define CH    64
#define W1C   67
#define GRPS  8
#define EPSV  1e-5f
#define SLOPEV 0.1f

typedef float f32x4 __attribute__((ext_vector_type(4)));
typedef short bf16x8 __attribute__((ext_vector_type(8)));
typedef unsigned short u16;
typedef u16 u16x4 __attribute__((ext_vector_type(4)));
typedef u16 u16x8 __attribute__((ext_vector_type(8)));

// workspace layout (float offsets)
#define WS_STATS1 0
#define WS_STATS2 64
#define WS_STATS3 128
#define WS_FLAG   192          // int flag: 1 => edges are int32
#define WS_YB     256                       // bf16 Y (and later bf16 z2pre): NPTS*CH/2 floats
#define WS_MX     (WS_YB + NPTS*CH/2)       // f32 Mx; later f32 z3pre
#define WS_MN     (WS_MX + NPTS*CH)         // f32 Mn

#define LDP 72                 // padded LDS row stride (bf16 elems)

__device__ __forceinline__ u16 f2bf(float f) {
    unsigned u = __float_as_uint(f);
    u += 0x7fff + ((u >> 16) & 1);          // round-nearest-even
    return (u16)(u >> 16);
}
__device__ __forceinline__ float bf2f(u16 h) {
    return __uint_as_float(((unsigned)h) << 16);
}

// ---------------------------------------------------------------- MFMA matmul family
// MODE 0: YB(bf16) = sig * W1s^T   (+ edge-dtype probe + stats zeroing in block 0)
// MODE 1: Z2B(bf16) = GN1(lrelu,max/min-select) * W2^T; stats2   (X0=Mx f32, X1=Mn f32)
// MODE 2: Z3(f32)   = GN2(lrelu) * W3^T; stats3                  (X0=Z2B bf16)
template<int MODE>
__global__ __launch_bounds__(256) void k_mm(
    const void* __restrict__ X0,
    const float* __restrict__ X1,
    const float* __restrict__ Wg,
    const float* __restrict__ statsIn, float invcnt,
    const float* __restrict__ gm, const float* __restrict__ bt,
    void* __restrict__ Out,
    float* __restrict__ statsOut,      // MODE 0: ws base (zero 192 floats)
    const int* __restrict__ e_i32, int* __restrict__ flag)
{
    __shared__ u16 Al[128*LDP];
    __shared__ u16 Wl[64*LDP];
    __shared__ float affA[64], affB[64];
    __shared__ float lacc[16];
    __shared__ int sfnd[4];
    int tid = threadIdx.x;
    int pbase = blockIdx.x * 128;
    int b = pbase >> 13;                      // batch index (NPB = 8192)

    if (MODE == 0 && blockIdx.x == 0) {
        if (tid < 192) statsOut[tid] = 0.f;   // zero stats1/2/3 (stream-ordered, race-free)
        // probe: odd dwords of the first 8192 dwords. int64 => high words all 0.
        int found = 0;
        #pragma unroll
        for (int i = 0; i < 16; ++i) {
            int idx = ((tid << 4) + i) * 2 + 1;
            found |= (e_i32[idx] != 0);
        }
        unsigned long long bl = __ballot(found);
        if ((tid & 63) == 0) sfnd[tid >> 6] = (bl != 0ull) ? 1 : 0;
    }
    if (MODE != 0) {
        if (tid < 64) {
            int g = tid >> 3;
            float sv = statsIn[b*16 + g*2 + 0];
            float qv = statsIn[b*16 + g*2 + 1];
            float mean = sv * invcnt;
            float var  = fmaf(-mean, mean, qv * invcnt);
            float rstd = rsqrtf(var + EPSV);
            float a = gm[tid] * rstd;
            affA[tid] = a;
            affB[tid] = fmaf(-mean, a, bt[tid]);
        }
    }
    if (tid < 16) lacc[tid] = 0.f;
    __syncthreads();
    if (MODE == 0 && blockIdx.x == 0 && tid == 0)
        *flag = sfnd[0] | sfnd[1] | sfnd[2] | sfnd[3];

    // ---- stage W (bf16): Wl[o][m] = W[o][m]
    {
        const int wstride = (MODE == 0) ? W1C : 64;
        #pragma unroll
        for (int i = 0; i < 16; ++i) {
            int e = tid + 256*i;
            int o = e >> 6, m = e & 63;
            Wl[o*LDP + m] = f2bf(Wg[o*wstride + m]);
        }
    }
    // ---- stage A (bf16): activated input rows
    #pragma unroll
    for (int it = 0; it < 8; ++it) {
        int fi = it*1024 + tid*4;
        int p = fi >> 6;                      // 0..127
        int m = fi & 63;
        float xv[4];
        if (MODE == 1) {
            f32x4 vx = *(const f32x4*)&((const float*)X0)[(pbase+p)*64 + m];
            f32x4 vn = *(const f32x4*)&X1[(pbase+p)*64 + m];
            #pragma unroll
            for (int j = 0; j < 4; ++j) {
                float a = affA[m+j];
                float x = (a < 0.f) ? vn[j] : vx[j];
                float z = fmaf(a, x, affB[m+j]);
                xv[j] = (z >= 0.f) ? z : SLOPEV * z;
            }
        } else if (MODE == 2) {
            u16x4 vh = *(const u16x4*)&((const u16*)X0)[(pbase+p)*64 + m];
            #pragma unroll
            for (int j = 0; j < 4; ++j) {
                float z = fmaf(affA[m+j], bf2f(vh[j]), affB[m+j]);
                xv[j] = (z >= 0.f) ? z : SLOPEV * z;
            }
        } else {
            f32x4 vx = *(const f32x4*)&((const float*)X0)[(pbase+p)*64 + m];
            #pragma unroll
            for (int j = 0; j < 4; ++j) xv[j] = vx[j];
        }
        #pragma unroll
        for (int j = 0; j < 4; ++j)
            Al[p*LDP + m + j] = f2bf(xv[j]);
    }
    __syncthreads();

    // ---- fragments + MFMA: wave w owns points [w*32, w*32+32), all 64 outputs
    int l = tid & 63, w = tid >> 6;
    int lr = l & 15;                          // row/col within tile
    int lk = l >> 4;                          // k-group (0..3)
    bf16x8 af[2][2], bw[4][2];
    #pragma unroll
    for (int pt = 0; pt < 2; ++pt)
        #pragma unroll
        for (int kh = 0; kh < 2; ++kh)
            af[pt][kh] = *(const bf16x8*)&Al[(w*32 + pt*16 + lr)*LDP + kh*32 + lk*8];
    #pragma unroll
    for (int ot = 0; ot < 4; ++ot)
        #pragma unroll
        for (int kh = 0; kh < 2; ++kh)
            bw[ot][kh] = *(const bf16x8*)&Wl[(ot*16 + lr)*LDP + kh*32 + lk*8];

    f32x4 acc[2][4];
    #pragma unroll
    for (int pt = 0; pt < 2; ++pt)
        #pragma unroll
        for (int ot = 0; ot < 4; ++ot) {
            f32x4 c = {0.f, 0.f, 0.f, 0.f};
            c = __builtin_amdgcn_mfma_f32_16x16x32_bf16(af[pt][0], bw[ot][0], c, 0, 0, 0);
            c = __builtin_amdgcn_mfma_f32_16x16x32_bf16(af[pt][1], bw[ot][1], c, 0, 0, 0);
            acc[pt][ot] = c;
        }

    // ---- store C: row = lk*4 + r, col = lr
    #pragma unroll
    for (int pt = 0; pt < 2; ++pt)
        #pragma unroll
        for (int ot = 0; ot < 4; ++ot)
            #pragma unroll
            for (int r = 0; r < 4; ++r) {
                int p = pbase + w*32 + pt*16 + lk*4 + r;
                int o = ot*16 + lr;
                if (MODE == 2) ((float*)Out)[p*64 + o] = acc[pt][ot][r];
                else           ((u16*)Out)[p*64 + o]  = f2bf(acc[pt][ot][r]);
            }

    // ---- fused next-GN stats
    if (MODE != 0) {
        #pragma unroll
        for (int ot = 0; ot < 4; ++ot) {
            float s = 0.f, ss = 0.f;
            #pragma unroll
            for (int pt = 0; pt < 2; ++pt)
                #pragma unroll
                for (int r = 0; r < 4; ++r) {
                    float v = acc[pt][ot][r];
                    s += v;
                    ss = fmaf(v, v, ss);
                }
            s += __shfl_xor(s, 16, 64);  ss += __shfl_xor(ss, 16, 64);
            s += __shfl_xor(s, 32, 64);  ss += __shfl_xor(ss, 32, 64);
            s += __shfl_xor(s, 1, 64);   ss += __shfl_xor(ss, 1, 64);
            s += __shfl_xor(s, 2, 64);   ss += __shfl_xor(ss, 2, 64);
            s += __shfl_xor(s, 4, 64);   ss += __shfl_xor(ss, 4, 64);
            if ((l & 7) == 0 && l < 16) {
                int g = ot*2 + (l >> 3);
                atomicAdd(&lacc[g*2 + 0], s);
                atomicAdd(&lacc[g*2 + 1], ss);
            }
        }
        __syncthreads();
        if (tid < 16)
            atomicAdd(&statsOut[b*16 + tid], lacc[tid]);
    }
}

// ---------------------------------------------------------------- edge pass (8 points/wave, ushort8 gathers)
template<bool IS32>
__device__ __forceinline__ void edge_loop8(const u16* __restrict__ Yb,
    const void* __restrict__ edg, const float* __restrict__ ef,
    int p, int il, const float (&yp)[8],
    const float (&w0)[8], const float (&w1)[8], const float (&w2)[8],
    float (&mx)[8], float (&mn)[8], float& s, float& ss)
{
    const int*       e32 = (const int*)edg;
    const long long* e64 = (const long long*)edg;
    #pragma unroll 4
    for (int k = 0; k < KNB; ++k) {
        int ei = p*KNB + k;
        int e  = IS32 ? __builtin_nontemporal_load(e32 + ei)
                      : (int)__builtin_nontemporal_load(e64 + ei);
        float c0 = __builtin_nontemporal_load(ef + ei*3 + 0);
        float c1 = __builtin_nontemporal_load(ef + ei*3 + 1);
        float c2 = __builtin_nontemporal_load(ef + ei*3 + 2);
        u16x8 q = *(const u16x8*)&Yb[e*64 + il*8];
        #pragma unroll
        for (int j = 0; j < 8; ++j) {
            float t = fmaf(c2, w2[j], fmaf(c1, w1[j], fmaf(c0, w0[j], bf2f(q[j]) - yp[j])));
            mx[j] = fmaxf(mx[j], t);
            mn[j] = fminf(mn[j], t);
            s += t;
            ss = fmaf(t, t, ss);
        }
    }
}

#define PPB_E 32
__global__ __launch_bounds__(256) void k_edge(const u16* __restrict__ Yb,
    const void* __restrict__ edg, const float* __restrict__ ef,
    const float* __restrict__ W1, const int* __restrict__ flag,
    float* __restrict__ Mx, float* __restrict__ Mn, float* __restrict__ stats1)
{
    __shared__ float lacc[16];
    int tid = threadIdx.x, lane = tid & 63, wv = tid >> 6;
    int il = lane & 7;                // channel octet = GN group
    int g8 = lane >> 3;               // point slot 0..7
    if (tid < 16) lacc[tid] = 0.f;

    int p = blockIdx.x * PPB_E + wv * 8 + g8;

    float w0[8], w1[8], w2[8], yp[8], mx[8], mn[8];
    #pragma unroll
    for (int j = 0; j < 8; ++j) {
        int ch = il*8 + j;
        w0[j] = W1[ch*W1C + 64];
        w1[j] = W1[ch*W1C + 65];
        w2[j] = W1[ch*W1C + 66];
    }
    u16x8 yh = *(const u16x8*)&Yb[p*64 + il*8];
    #pragma unroll
    for (int j = 0; j < 8; ++j) {
        yp[j] = bf2f(yh[j]);
        mx[j] = -3.4e38f;
        mn[j] =  3.4e38f;
    }
    float s = 0.f, ss = 0.f;
    bool is32 = (*flag != 0);
    __syncthreads();   // lacc init visible before atomics

    if (is32) edge_loop8<true >(Yb, edg, ef, p, il, yp, w0, w1, w2, mx, mn, s, ss);
    else      edge_loop8<false>(Yb, edg, ef, p, il, yp, w0, w1, w2, mx, mn, s, ss);

    f32x4 mxa = {mx[0], mx[1], mx[2], mx[3]};
    f32x4 mxb = {mx[4], mx[5], mx[6], mx[7]};
    f32x4 mna = {mn[0], mn[1], mn[2], mn[3]};
    f32x4 mnb = {mn[4], mn[5], mn[6], mn[7]};
    __builtin_nontemporal_store(mxa, (f32x4*)(Mx + p*64 + il*8));
    __builtin_nontemporal_store(mxb, (f32x4*)(Mx + p*64 + il*8 + 4));
    __builtin_nontemporal_store(mna, (f32x4*)(Mn + p*64 + il*8));
    __builtin_nontemporal_store(mnb, (f32x4*)(Mn + p*64 + il*8 + 4));

    // s,ss are complete sums for GN group il of this point; reduce across the 8 point-slots
    s += __shfl_xor(s,  8, 64);  ss += __shfl_xor(ss,  8, 64);
    s += __shfl_xor(s, 16, 64);  ss += __shfl_xor(ss, 16, 64);
    s += __shfl_xor(s, 32, 64);  ss += __shfl_xor(ss, 32, 64);
    if (lane < 8) {
        atomicAdd(&lacc[lane*2 + 0], s);
        atomicAdd(&lacc[lane*2 + 1], ss);
    }
    __syncthreads();
    if (tid < 16) {
        int b = (blockIdx.x * PPB_E) / NPB;
        atomicAdd(&stats1[b*16 + tid], lacc[tid]);
    }
}

// ---------------------------------------------------------------- final GN + lrelu -> out
__global__ __launch_bounds__(256) void k_out(const float* __restrict__ Vpre,
    const float* __restrict__ stats, float invcnt,
    const float* __restrict__ gm, const float* __restrict__ bt,
    float* __restrict__ out)
{
    int idx = blockIdx.x * blockDim.x + threadIdx.x;   // one float4 per thread
    int p  = idx >> 4;
    int m0 = (idx & 15) << 2;
    int b  = p >> 13;                                  // p / 8192
    int g  = m0 >> 3;
    float sv = stats[b*16 + g*2 + 0];
    float qv = stats[b*16 + g*2 + 1];
    float mean = sv * invcnt;
    float var  = fmaf(-mean, mean, qv * invcnt);
    float rstd = rsqrtf(var + EPSV);
    float4 v = reinterpret_cast<const float4*>(Vpre)[idx];
    float in[4] = {v.x, v.y, v.z, v.w};
    float r[4];
    #pragma unroll
    for (int j = 0; j < 4; ++j) {
        float aa = gm[m0+j] * rstd;
        float z  = fmaf(aa, in[j] - mean, bt[m0+j]);
        r[j] = (z >= 0.f) ? z : SLOPEV * z;
    }
    float4 o4 = {r[0], r[1], r[2], r[3]};
    reinterpret_cast<float4*>(out)[idx] = o4;
}

// ---------------------------------------------------------------- launch
extern "C" void kernel_launch(void* const* d_in, const int* in_sizes, int n_in,
                              void* d_out, int out_size, void* d_ws, size_t ws_size,
                              hipStream_t stream)
{
    const float* sig = (const float*)d_in[0];
    const void*  edg = d_in[1];
    const float* ef  = (const float*)d_in[2];
    const float* W1  = (const float*)d_in[3];
    const float* g1  = (const float*)d_in[4];
    const float* b1  = (const float*)d_in[5];
    const float* W2  = (const float*)d_in[6];
    const float* g2  = (const float*)d_in[7];
    const float* b2  = (const float*)d_in[8];
    const float* W3  = (const float*)d_in[9];
    const float* g3  = (const float*)d_in[10];
    const float* b3  = (const float*)d_in[11];
    float* out = (float*)d_out;
    float* ws  = (float*)d_ws;
    u16*   yb  = (u16*)(ws + WS_YB);

    k_mm<0><<<NPTS/128, 256, 0, stream>>>(sig, nullptr, W1, nullptr, 0.f,
                                          nullptr, nullptr, yb, ws,
                                          (const int*)edg, (int*)(ws + WS_FLAG));
    k_edge<<<NPTS/PPB_E, 256, 0, stream>>>(yb, edg, ef, W1,
                                           (const int*)(ws + WS_FLAG),
                                           ws + WS_MX, ws + WS_MN, ws + WS_STATS1);
    k_mm<1><<<NPTS/128, 256, 0, stream>>>(ws + WS_MX, ws + WS_MN, W2,
                                          ws + WS_STATS1, 1.f/(float)(NPB*KNB*8),
                                          g1, b1, yb, ws + WS_STATS2,
                                          nullptr, nullptr);
    k_mm<2><<<NPTS/128, 256, 0, stream>>>(yb, nullptr, W3,
                                          ws + WS_STATS2, 1.f/(float)(NPB*8),
                                          g2, b2, ws + WS_MX, ws + WS_STATS3,
                                          nullptr, nullptr);
    k_out<<<(NPTS*CH/4)/256, 256, 0, stream>>>(ws + WS_MX, ws + WS_STATS3,
                                         1.f/(float)(NPB*8), g3, b3, out);
}

// Round 7
// 56.861 us; speedup vs baseline: 3.9497x; 1.1245x over previous
//
#include <hip/hip_runtime.h>

#define NB    4
#define NPB   8192
#define NPTS  (NB*NPB)      // 32768
#define KNB   32
#define CH    64
#define W1C   67
#define GRPS  8
#define EPSV  1e-5f
#define SLOPEV 0.1f

typedef float f32x4 __attribute__((ext_vector_type(4)));
typedef short bf16x8 __attribute__((ext_vector_type(8)));
typedef unsigned short u16;
typedef u16 u16x4 __attribute__((ext_vector_type(4)));
typedef u16 u16x8 __attribute__((ext_vector_type(8)));

// workspace layout (float offsets) — all big buffers bf16 now
#define WS_STATS1 0
#define WS_STATS2 64
#define WS_STATS3 128
#define WS_FLAG   192          // int flag: 1 => edges are int32
#define WS_YB     256                        // bf16 Y, later bf16 z2pre
#define WS_MX     (WS_YB + NPTS*CH/2)        // bf16 Mx, later bf16 z3pre
#define WS_MN     (WS_MX + NPTS*CH/2)        // bf16 Mn

#define LDP 72                 // padded LDS row stride (bf16 elems) for k_mm

__device__ __forceinline__ u16 f2bf(float f) {
    unsigned u = __float_as_uint(f);
    u += 0x7fff + ((u >> 16) & 1);          // round-nearest-even
    return (u16)(u >> 16);
}
__device__ __forceinline__ float bf2f(u16 h) {
    return __uint_as_float(((unsigned)h) << 16);
}

// ---------------------------------------------------------------- MFMA matmul family
// MODE 0: YB(bf16) = sig * W1s^T   (+ edge-dtype probe + stats zeroing in block 0)
// MODE 1: Z2B(bf16) = GN1(lrelu,max/min-select) * W2^T; stats2   (X0=Mx bf16, X1=Mn bf16)
// MODE 2: Z3B(bf16) = GN2(lrelu) * W3^T; stats3                  (X0=Z2B bf16)
template<int MODE>
__global__ __launch_bounds__(256) void k_mm(
    const void* __restrict__ X0,
    const void* __restrict__ X1,
    const float* __restrict__ Wg,
    const float* __restrict__ statsIn, float invcnt,
    const float* __restrict__ gm, const float* __restrict__ bt,
    void* __restrict__ Out,
    float* __restrict__ statsOut,      // MODE 0: ws base (zero 192 floats)
    const int* __restrict__ e_i32, int* __restrict__ flag)
{
    __shared__ u16 Al[128*LDP];
    __shared__ u16 Wl[64*LDP];
    __shared__ float affA[64], affB[64];
    __shared__ float lacc[16];
    __shared__ int sfnd[4];
    int tid = threadIdx.x;
    int pbase = blockIdx.x * 128;
    int b = pbase >> 13;                      // batch index (NPB = 8192)

    if (MODE == 0 && blockIdx.x == 0) {
        if (tid < 192) statsOut[tid] = 0.f;   // zero stats1/2/3 (stream-ordered, race-free)
        // probe: odd dwords of the first 8192 dwords. int64 => high words all 0.
        int found = 0;
        #pragma unroll
        for (int i = 0; i < 16; ++i) {
            int idx = ((tid << 4) + i) * 2 + 1;
            found |= (e_i32[idx] != 0);
        }
        unsigned long long bl = __ballot(found);
        if ((tid & 63) == 0) sfnd[tid >> 6] = (bl != 0ull) ? 1 : 0;
    }
    if (MODE != 0) {
        if (tid < 64) {
            int g = tid >> 3;
            float sv = statsIn[b*16 + g*2 + 0];
            float qv = statsIn[b*16 + g*2 + 1];
            float mean = sv * invcnt;
            float var  = fmaf(-mean, mean, qv * invcnt);
            float rstd = rsqrtf(var + EPSV);
            float a = gm[tid] * rstd;
            affA[tid] = a;
            affB[tid] = fmaf(-mean, a, bt[tid]);
        }
    }
    if (tid < 16) lacc[tid] = 0.f;
    __syncthreads();
    if (MODE == 0 && blockIdx.x == 0 && tid == 0)
        *flag = sfnd[0] | sfnd[1] | sfnd[2] | sfnd[3];

    // ---- stage W (bf16): Wl[o][m] = W[o][m]
    {
        const int wstride = (MODE == 0) ? W1C : 64;
        #pragma unroll
        for (int i = 0; i < 16; ++i) {
            int e = tid + 256*i;
            int o = e >> 6, m = e & 63;
            Wl[o*LDP + m] = f2bf(Wg[o*wstride + m]);
        }
    }
    // ---- stage A (bf16): activated input rows
    #pragma unroll
    for (int it = 0; it < 8; ++it) {
        int fi = it*1024 + tid*4;
        int p = fi >> 6;                      // 0..127
        int m = fi & 63;
        float xv[4];
        if (MODE == 1) {
            u16x4 vx = *(const u16x4*)&((const u16*)X0)[(pbase+p)*64 + m];
            u16x4 vn = *(const u16x4*)&((const u16*)X1)[(pbase+p)*64 + m];
            #pragma unroll
            for (int j = 0; j < 4; ++j) {
                float a = affA[m+j];
                float x = (a < 0.f) ? bf2f(vn[j]) : bf2f(vx[j]);
                float z = fmaf(a, x, affB[m+j]);
                xv[j] = (z >= 0.f) ? z : SLOPEV * z;
            }
        } else if (MODE == 2) {
            u16x4 vh = *(const u16x4*)&((const u16*)X0)[(pbase+p)*64 + m];
            #pragma unroll
            for (int j = 0; j < 4; ++j) {
                float z = fmaf(affA[m+j], bf2f(vh[j]), affB[m+j]);
                xv[j] = (z >= 0.f) ? z : SLOPEV * z;
            }
        } else {
            f32x4 vx = *(const f32x4*)&((const float*)X0)[(pbase+p)*64 + m];
            #pragma unroll
            for (int j = 0; j < 4; ++j) xv[j] = vx[j];
        }
        #pragma unroll
        for (int j = 0; j < 4; ++j)
            Al[p*LDP + m + j] = f2bf(xv[j]);
    }
    __syncthreads();

    // ---- fragments + MFMA: wave w owns points [w*32, w*32+32), all 64 outputs
    int l = tid & 63, w = tid >> 6;
    int lr = l & 15;                          // row/col within tile
    int lk = l >> 4;                          // k-group (0..3)
    bf16x8 af[2][2], bw[4][2];
    #pragma unroll
    for (int pt = 0; pt < 2; ++pt)
        #pragma unroll
        for (int kh = 0; kh < 2; ++kh)
            af[pt][kh] = *(const bf16x8*)&Al[(w*32 + pt*16 + lr)*LDP + kh*32 + lk*8];
    #pragma unroll
    for (int ot = 0; ot < 4; ++ot)
        #pragma unroll
        for (int kh = 0; kh < 2; ++kh)
            bw[ot][kh] = *(const bf16x8*)&Wl[(ot*16 + lr)*LDP + kh*32 + lk*8];

    f32x4 acc[2][4];
    #pragma unroll
    for (int pt = 0; pt < 2; ++pt)
        #pragma unroll
        for (int ot = 0; ot < 4; ++ot) {
            f32x4 c = {0.f, 0.f, 0.f, 0.f};
            c = __builtin_amdgcn_mfma_f32_16x16x32_bf16(af[pt][0], bw[ot][0], c, 0, 0, 0);
            c = __builtin_amdgcn_mfma_f32_16x16x32_bf16(af[pt][1], bw[ot][1], c, 0, 0, 0);
            acc[pt][ot] = c;
        }

    // ---- store C (bf16): row = lk*4 + r, col = lr
    #pragma unroll
    for (int pt = 0; pt < 2; ++pt)
        #pragma unroll
        for (int ot = 0; ot < 4; ++ot)
            #pragma unroll
            for (int r = 0; r < 4; ++r) {
                int p = pbase + w*32 + pt*16 + lk*4 + r;
                int o = ot*16 + lr;
                ((u16*)Out)[p*64 + o] = f2bf(acc[pt][ot][r]);
            }

    // ---- fused next-GN stats (f32 accs, pre-quantization)
    if (MODE != 0) {
        #pragma unroll
        for (int ot = 0; ot < 4; ++ot) {
            float s = 0.f, ss = 0.f;
            #pragma unroll
            for (int pt = 0; pt < 2; ++pt)
                #pragma unroll
                for (int r = 0; r < 4; ++r) {
                    float v = acc[pt][ot][r];
                    s += v;
                    ss = fmaf(v, v, ss);
                }
            s += __shfl_xor(s, 16, 64);  ss += __shfl_xor(ss, 16, 64);
            s += __shfl_xor(s, 32, 64);  ss += __shfl_xor(ss, 32, 64);
            s += __shfl_xor(s, 1, 64);   ss += __shfl_xor(ss, 1, 64);
            s += __shfl_xor(s, 2, 64);   ss += __shfl_xor(ss, 2, 64);
            s += __shfl_xor(s, 4, 64);   ss += __shfl_xor(ss, 4, 64);
            if ((l & 7) == 0 && l < 16) {
                int g = ot*2 + (l >> 3);
                atomicAdd(&lacc[g*2 + 0], s);
                atomicAdd(&lacc[g*2 + 1], ss);
            }
        }
        __syncthreads();
        if (tid < 16)
            atomicAdd(&statsOut[b*16 + tid], lacc[tid]);
    }
}

// ---------------------------------------------------------------- edge pass
// 8 points/wave, LDS-staged {c0,c1,c2,byteoff} per (pt,k), bf16 Mx/Mn out.
#define PPB_E 32
#define SEDS  (KNB*4 + 4)      // per-point float stride in sed: banks decorrelate across pts
__global__ __launch_bounds__(256) void k_edge(const u16* __restrict__ Yb,
    const void* __restrict__ edg, const float* __restrict__ ef,
    const float* __restrict__ W1, const int* __restrict__ flag,
    u16* __restrict__ Mx, u16* __restrict__ Mn, float* __restrict__ stats1)
{
    __shared__ float sed[PPB_E*SEDS];
    __shared__ float lacc[16];
    int tid = threadIdx.x;
    if (tid < 16) lacc[tid] = 0.f;

    // ---- stage edges+coords, precompute Y byte offsets
    {
        bool is32 = (*flag != 0);
        const int*       e32 = (const int*)edg;
        const long long* e64 = (const long long*)edg;
        int ebase = blockIdx.x * (PPB_E*KNB);
        #pragma unroll
        for (int i = 0; i < 4; ++i) {
            int idx = tid + i*256;            // 0..1023 = pt*KNB + k
            int gi  = ebase + idx;
            int e   = is32 ? __builtin_nontemporal_load(e32 + gi)
                           : (int)__builtin_nontemporal_load(e64 + gi);
            int pt = idx >> 5, k = idx & 31;
            float* d = &sed[pt*SEDS + k*4];
            d[0] = __builtin_nontemporal_load(ef + gi*3 + 0);
            d[1] = __builtin_nontemporal_load(ef + gi*3 + 1);
            d[2] = __builtin_nontemporal_load(ef + gi*3 + 2);
            d[3] = __int_as_float(e << 7);    // e * 128 bytes (64 ch * 2B)
        }
    }

    int lane = tid & 63, wv = tid >> 6;
    int il = lane & 7;                // channel octet = GN group
    int g8 = lane >> 3;               // point slot 0..7
    int lpt = wv*8 + g8;              // local point 0..31
    int p = blockIdx.x * PPB_E + lpt;

    float w0[8], w1[8], w2[8], yp[8], mx[8], mn[8];
    #pragma unroll
    for (int j = 0; j < 8; ++j) {
        int ch = il*8 + j;
        w0[j] = W1[ch*W1C + 64];
        w1[j] = W1[ch*W1C + 65];
        w2[j] = W1[ch*W1C + 66];
    }
    u16x8 yh = *(const u16x8*)&Yb[p*64 + il*8];
    #pragma unroll
    for (int j = 0; j < 8; ++j) {
        yp[j] = bf2f(yh[j]);
        mx[j] = -3.4e38f;
        mn[j] =  3.4e38f;
    }
    float s = 0.f, ss = 0.f;
    __syncthreads();

    const char* Ybase = (const char*)Yb + il*16;
    const float* sp = &sed[lpt*SEDS];
    #pragma unroll 8
    for (int k = 0; k < KNB; ++k) {
        f32x4 m4 = *(const f32x4*)(sp + k*4);
        u16x8 q = *(const u16x8*)(Ybase + __float_as_int(m4[3]));
        float c0 = m4[0], c1 = m4[1], c2 = m4[2];
        #pragma unroll
        for (int j = 0; j < 8; ++j) {
            float t = fmaf(c2, w2[j], fmaf(c1, w1[j], fmaf(c0, w0[j], bf2f(q[j]) - yp[j])));
            mx[j] = fmaxf(mx[j], t);
            mn[j] = fminf(mn[j], t);
            s += t;
            ss = fmaf(t, t, ss);
        }
    }

    u16x8 hx, hn;
    #pragma unroll
    for (int j = 0; j < 8; ++j) { hx[j] = f2bf(mx[j]); hn[j] = f2bf(mn[j]); }
    __builtin_nontemporal_store(hx, (u16x8*)(Mx + p*64 + il*8));
    __builtin_nontemporal_store(hn, (u16x8*)(Mn + p*64 + il*8));

    // s,ss are complete sums for GN group il of this point; reduce across the 8 point-slots
    s += __shfl_xor(s,  8, 64);  ss += __shfl_xor(ss,  8, 64);
    s += __shfl_xor(s, 16, 64);  ss += __shfl_xor(ss, 16, 64);
    s += __shfl_xor(s, 32, 64);  ss += __shfl_xor(ss, 32, 64);
    if (lane < 8) {
        atomicAdd(&lacc[lane*2 + 0], s);
        atomicAdd(&lacc[lane*2 + 1], ss);
    }
    __syncthreads();
    if (tid < 16) {
        int b = (blockIdx.x * PPB_E) / NPB;
        atomicAdd(&stats1[b*16 + tid], lacc[tid]);
    }
}

// ---------------------------------------------------------------- final GN + lrelu -> out (bf16 in, f32 out)
__global__ __launch_bounds__(256) void k_out(const u16* __restrict__ Vpre,
    const float* __restrict__ stats, float invcnt,
    const float* __restrict__ gm, const float* __restrict__ bt,
    float* __restrict__ out)
{
    int idx = blockIdx.x * blockDim.x + threadIdx.x;   // one float4 per thread
    int p  = idx >> 4;
    int m0 = (idx & 15) << 2;
    int b  = p >> 13;                                  // p / 8192
    int g  = m0 >> 3;
    float sv = stats[b*16 + g*2 + 0];
    float qv = stats[b*16 + g*2 + 1];
    float mean = sv * invcnt;
    float var  = fmaf(-mean, mean, qv * invcnt);
    float rstd = rsqrtf(var + EPSV);
    u16x4 v = *(const u16x4*)&Vpre[idx*4];
    float r[4];
    #pragma unroll
    for (int j = 0; j < 4; ++j) {
        float aa = gm[m0+j] * rstd;
        float z  = fmaf(aa, bf2f(v[j]) - mean, bt[m0+j]);
        r[j] = (z >= 0.f) ? z : SLOPEV * z;
    }
    f32x4 o4 = {r[0], r[1], r[2], r[3]};
    *(f32x4*)&out[idx*4] = o4;
}

// ---------------------------------------------------------------- launch
extern "C" void kernel_launch(void* const* d_in, const int* in_sizes, int n_in,
                              void* d_out, int out_size, void* d_ws, size_t ws_size,
                              hipStream_t stream)
{
    const float* sig = (const float*)d_in[0];
    const void*  edg = d_in[1];
    const float* ef  = (const float*)d_in[2];
    const float* W1  = (const float*)d_in[3];
    const float* g1  = (const float*)d_in[4];
    const float* b1  = (const float*)d_in[5];
    const float* W2  = (const float*)d_in[6];
    const float* g2  = (const float*)d_in[7];
    const float* b2  = (const float*)d_in[8];
    const float* W3  = (const float*)d_in[9];
    const float* g3  = (const float*)d_in[10];
    const float* b3  = (const float*)d_in[11];
    float* out = (float*)d_out;
    float* ws  = (float*)d_ws;
    u16*   yb  = (u16*)(ws + WS_YB);
    u16*   mxb = (u16*)(ws + WS_MX);
    u16*   mnb = (u16*)(ws + WS_MN);

    k_mm<0><<<NPTS/128, 256, 0, stream>>>(sig, nullptr, W1, nullptr, 0.f,
                                          nullptr, nullptr, yb, ws,
                                          (const int*)edg, (int*)(ws + WS_FLAG));
    k_edge<<<NPTS/PPB_E, 256, 0, stream>>>(yb, edg, ef, W1,
                                           (const int*)(ws + WS_FLAG),
                                           mxb, mnb, ws + WS_STATS1);
    k_mm<1><<<NPTS/128, 256, 0, stream>>>(mxb, mnb, W2,
                                          ws + WS_STATS1, 1.f/(float)(NPB*KNB*8),
                                          g1, b1, yb, ws + WS_STATS2,
                                          nullptr, nullptr);
    k_mm<2><<<NPTS/128, 256, 0, stream>>>(yb, nullptr, W3,
                                          ws + WS_STATS2, 1.f/(float)(NPB*8),
                                          g2, b2, mxb, ws + WS_STATS3,
                                          nullptr, nullptr);
    k_out<<<(NPTS*CH/4)/256, 256, 0, stream>>>(mxb, ws + WS_STATS3,
                                         1.f/(float)(NPB*8), g3, b3, out);
}